// Round 10
// baseline (762.688 us; speedup 1.0000x reference)
//
#include <hip/hip_runtime.h>
#include <hip/hip_bf16.h>
#include <math.h>

#define ODIM 592002L
#define WRB  589824L
#define NB 8

typedef __hip_bfloat16 bf16;
typedef __bf16  bf16x8 __attribute__((ext_vector_type(8)));
typedef float   f32x16 __attribute__((ext_vector_type(16)));
typedef short   s16x8  __attribute__((ext_vector_type(8)));

__device__ __forceinline__ float b2f(bf16 x) { return __bfloat162float(x); }
__device__ __forceinline__ bf16 f2b(float x) { return __float2bfloat16(x); }
__device__ __forceinline__ bf16x8 bzero() { return __builtin_bit_cast(bf16x8, (s16x8)0); }

// ---------------- hypernet: h2 = (hp*W1^T + b1) @ W2^T + b2 ----------------
__global__ __launch_bounds__(256) void hyper_h(
    const float* __restrict__ hp, const float* __restrict__ W1,
    const float* __restrict__ b1, const float* __restrict__ W2,
    const float* __restrict__ b2, float* __restrict__ h2out)
{
    __shared__ float h1[NB][32];
    int t = threadIdx.x;
    int b = t >> 5, i = t & 31;
    h1[b][i] = hp[b] * W1[i] + b1[i];
    __syncthreads();
    float acc = b2[i];
    #pragma unroll
    for (int j = 0; j < 32; ++j) acc += h1[b][j] * W2[i * 32 + j];
    h2out[b * 32 + i] = acc;
}

// ------- w = tanh(h2 @ Wo^T + bo) -> bf16, + per-block |w| partials (f32) --
__global__ __launch_bounds__(256) void genw(
    const float* __restrict__ Wo, const float* __restrict__ bo,
    const float* __restrict__ h2, bf16* __restrict__ wfb,
    float* __restrict__ part)
{
    __shared__ float h2s[256];
    __shared__ float red[256];
    int t = threadIdx.x;
    h2s[t] = h2[t];
    __syncthreads();
    long o = (long)blockIdx.x * 256 + t;
    float absacc[NB];
    #pragma unroll
    for (int b = 0; b < NB; ++b) absacc[b] = 0.f;
    if (o < ODIM) {
        float row[32];
        const float4* wp = (const float4*)(Wo + o * 32);
        #pragma unroll
        for (int q = 0; q < 8; ++q) {
            float4 v = wp[q];
            row[q*4+0] = v.x; row[q*4+1] = v.y; row[q*4+2] = v.z; row[q*4+3] = v.w;
        }
        float bias = bo[o];
        #pragma unroll
        for (int b = 0; b < NB; ++b) {
            float acc = bias;
            #pragma unroll
            for (int k = 0; k < 32; ++k) acc += h2s[b*32+k] * row[k];
            float w = tanhf(acc);
            wfb[(long)b * ODIM + o] = f2b(w);
            absacc[b] = fabsf(w);
        }
    }
    for (int b = 0; b < NB; ++b) {
        red[t] = absacc[b];
        __syncthreads();
        for (int s = 128; s > 0; s >>= 1) {
            if (t < s) red[t] += red[t + s];
            __syncthreads();
        }
        if (t == 0) part[(long)blockIdx.x * NB + b] = red[0];
        __syncthreads();
    }
}

__global__ __launch_bounds__(256) void l1_reduce(
    const float* __restrict__ part, int nblk, float* __restrict__ outp)
{
    __shared__ float red[256];
    int t = threadIdx.x; int b = t & 7, ch = t >> 3;
    float s = 0.f;
    for (int i = ch; i < nblk; i += 32) s += part[(long)i * 8 + b];
    red[t] = s;
    __syncthreads();
    for (int st = 128; st >= 8; st >>= 1) {
        if (t < st) red[t] += red[t + st];
        __syncthreads();
    }
    if (t < 8) outp[t] = red[t];
}

// ---- repack ALL layers into per-lane MFMA fragment order (one launch) ----
// frag fid = ((pass*9 + tap)*4 + k4)*2 + oc_half ; then [lane][8].
__global__ __launch_bounds__(256) void repack_all(
    const bf16* __restrict__ wfb, bf16* __restrict__ wr)
{
    int i = blockIdx.x * 256 + threadIdx.x;   // 0..WRB-1
    int b = blockIdx.y;
    if (i >= (int)WRB) return;
    int roff, koff, dual = 0;
    if      (i < 36864)  { roff = 0;      koff = 1152;  }
    else if (i < 73728)  { roff = 36864;  koff = 38016; }
    else if (i < 110592) { roff = 73728;  koff = 74880; }
    else if (i < 147456) { roff = 110592; koff = 111744;}
    else if (i < 184320) { roff = 147456; koff = 148608;}
    else if (i < 221184) { roff = 184320; koff = 185472;}
    else if (i < 258048) { roff = 221184; koff = 222336;}
    else if (i < 331776) { roff = 258048; koff = 259200; dual = 1; }
    else if (i < 368640) { roff = 331776; koff = 332928;}
    else if (i < 442368) { roff = 368640; koff = 369792; dual = 1; }
    else if (i < 479232) { roff = 442368; koff = 443520;}
    else if (i < 552960) { roff = 479232; koff = 480384; dual = 1; }
    else                 { roff = 552960; koff = 554112;}
    int li = i - roff;
    int Cinfull = dual ? 128 : 64;
    int fid = li >> 9;
    int lane = (li >> 3) & 63;
    int j = li & 7;
    int h = fid & 1;
    int kk = fid >> 1;
    int k4 = kk & 3;
    int tapq = kk >> 2;
    int tap = tapq % 9;
    int pass = tapq / 9;
    int oc = h * 32 + (lane & 31);
    int icf = pass * 64 + k4 * 16 + (lane >> 5) * 8 + j;
    wr[(long)b * WRB + i] =
        wfb[(long)b * ODIM + koff + ((long)oc * Cinfull + icf) * 9 + tap];
}

// ---------------- LDS staging: PLAIN(0) / POOL(1) / UP2(2) ----------------
template<int TR, int TC, int MODE>
__device__ __forceinline__ void stage_tile(
    const bf16* __restrict__ src, int Hc, int Wc, int y0, int x0,
    bf16* lin, int t)
{
    const int XL = TC + 2;
    const int total = (TR + 2) * XL * 8;
    for (int idx = t; idx < total; idx += 256) {
        const int g = idx & 7;
        const int rem = idx >> 3;
        const int xl = rem % XL;
        const int gy = y0 + rem / XL - 1, gx = x0 + xl - 1;
        bf16x8 v = bzero();
        if ((unsigned)gy < (unsigned)Hc && (unsigned)gx < (unsigned)Wc) {
            if constexpr (MODE == 0) {
                v = *(const bf16x8*)(src + (((long)gy * Wc) + gx) * 64 + g * 8);
            } else if constexpr (MODE == 1) {
                const int Ws = Wc * 2;
                const bf16* p = src + (((long)(gy*2) * Ws) + gx*2) * 64 + g * 8;
                bf16x8 aa = *(const bf16x8*)p;
                bf16x8 bb = *(const bf16x8*)(p + 64);
                bf16x8 cc = *(const bf16x8*)(p + (long)Ws * 64);
                bf16x8 dd = *(const bf16x8*)(p + (long)Ws * 64 + 64);
                #pragma unroll
                for (int j = 0; j < 8; ++j) {
                    float m = fmaxf(fmaxf((float)aa[j], (float)bb[j]),
                                    fmaxf((float)cc[j], (float)dd[j]));
                    v[j] = (__bf16)m;
                }
            } else {
                const int Hs = Hc >> 1, Ws = Wc >> 1;
                const float sy = (float)(Hs - 1) / (float)(Hc - 1);
                const float sx = (float)(Ws - 1) / (float)(Wc - 1);
                float ys = gy * sy, xs = gx * sx;
                int yy0 = (int)ys, xx0 = (int)xs;
                int yy1 = min(yy0 + 1, Hs - 1), xx1 = min(xx0 + 1, Ws - 1);
                float wy = ys - (float)yy0, wx = xs - (float)xx0;
                bf16x8 q00 = *(const bf16x8*)(src + ((long)yy0*Ws + xx0)*64 + g*8);
                bf16x8 q01 = *(const bf16x8*)(src + ((long)yy0*Ws + xx1)*64 + g*8);
                bf16x8 q10 = *(const bf16x8*)(src + ((long)yy1*Ws + xx0)*64 + g*8);
                bf16x8 q11 = *(const bf16x8*)(src + ((long)yy1*Ws + xx1)*64 + g*8);
                #pragma unroll
                for (int j = 0; j < 8; ++j) {
                    float r0 = (float)q00[j]*(1.f-wx) + (float)q01[j]*wx;
                    float r1 = (float)q10[j]*(1.f-wx) + (float)q11[j]*wx;
                    v[j] = (__bf16)(r0*(1.f-wy) + r1*wy);
                }
            }
        }
        long byte = (((long)rem) * 128 + g * 16) ^ ((xl & 7) << 4);
        *(bf16x8*)((char*)lin + byte) = v;
    }
}

// ---------------- MFMA implicit-GEMM 3x3 conv, 64 oc, NHWC bf16 -----------
// Tile TR=16 x TC=32 = 512 px. 4 waves; wave w owns ADJACENT rows 4w..4w+3,
// both oc-halves. Register discipline: unroll-1 on k4 AND dxi, inline addr
// math (no runtime-indexed arrays), sched_barrier(0) after EVERY dxi iter
// -> live set per region: 128 acc + 6 bfr + 2 af + temps < 256 unified regs.
template<int MODE>
__global__ __launch_bounds__(256, 2) void conv_mfma(
    const bf16* __restrict__ src1, const bf16* __restrict__ src2,
    int Hc, int Wc,
    const bf16* __restrict__ wr, long roff,
    const bf16* __restrict__ wfb, int boff,
    bf16* __restrict__ outp)
{
    const int TR = 16, TC = 32, XL = TC + 2;
    __shared__ bf16 lin[(TR + 2) * XL * 64];     // 78336 B
    __shared__ float biasf[64];
    const int t = threadIdx.x;
    const int lane = t & 63;
    const int w = t >> 6;
    const int b = blockIdx.z;
    const int y0 = blockIdx.y * TR;
    const int x0 = blockIdx.x * TC;
    const int lx = lane & 31;

    f32x16 acc[4][2];
    #pragma unroll
    for (int r = 0; r < 4; ++r) {
        acc[r][0] = {}; acc[r][1] = {};
    }

    const bf16* wl = wr + (long)b * WRB + roff;
    if (t < 64) biasf[t] = b2f(wfb[(long)b * ODIM + boff + t]);

    const int icbl = (lane >> 5) * 16;
    const int wrow = 4 * w;

    auto kpass = [&](int p) {
        #pragma unroll 1
        for (int k4 = 0; k4 < 4; ++k4) {
            #pragma unroll 1
            for (int dxi = 0; dxi < 3; ++dxi) {
                const int xl = lx + dxi;
                const int co = xl * 128 + (((k4 * 32 + icbl) ^ ((xl & 7) << 4)));
                bf16x8 bfr[6];
                #pragma unroll
                for (int rr = 0; rr < 6; ++rr)
                    bfr[rr] = *(const bf16x8*)((const char*)lin + (wrow + rr) * (XL * 128) + co);
                #pragma unroll
                for (int dy = 0; dy < 3; ++dy) {
                    const int fid = ((p * 9 + dy * 3 + dxi) * 4 + k4) * 2;
                    const bf16* pk = wl + ((long)fid << 9) + (lane << 3);
                    bf16x8 a0 = *(const bf16x8*)pk;
                    bf16x8 a1 = *(const bf16x8*)(pk + 512);
                    #pragma unroll
                    for (int r = 0; r < 4; ++r) {
                        acc[r][0] = __builtin_amdgcn_mfma_f32_32x32x16_bf16(a0, bfr[r + dy], acc[r][0], 0, 0, 0);
                        acc[r][1] = __builtin_amdgcn_mfma_f32_32x32x16_bf16(a1, bfr[r + dy], acc[r][1], 0, 0, 0);
                    }
                }
                __builtin_amdgcn_sched_barrier(0);
            }
        }
    };

    stage_tile<TR, TC, MODE>(src1, Hc, Wc, y0, x0, lin, t);
    __syncthreads();
    kpass(0);
    if (src2) {
        __syncthreads();
        stage_tile<TR, TC, 0>(src2, Hc, Wc, y0, x0, lin, t);
        __syncthreads();
        kpass(1);
    }

    // ---- epilogue: acc -> LDS [pix][oc] (swizzled) -> coalesced store ----
    __syncthreads();
    #pragma unroll
    for (int r = 0; r < 4; ++r) {
        const int pixidx = (wrow + r) * TC + lx;
        const int psw = (pixidx & 7) << 4;
        #pragma unroll
        for (int ocs = 0; ocs < 2; ++ocs) {
            const f32x16& A = acc[r][ocs];
            #pragma unroll
            for (int q = 0; q < 4; ++q) {
                const int oc0 = ocs * 32 + 8 * q + 4 * (lane >> 5);
                ushort4 pk;
                float v0 = fmaxf(A[4*q+0] + biasf[oc0 + 0], 0.f);
                float v1 = fmaxf(A[4*q+1] + biasf[oc0 + 1], 0.f);
                float v2 = fmaxf(A[4*q+2] + biasf[oc0 + 2], 0.f);
                float v3 = fmaxf(A[4*q+3] + biasf[oc0 + 3], 0.f);
                pk.x = __builtin_bit_cast(unsigned short, f2b(v0));
                pk.y = __builtin_bit_cast(unsigned short, f2b(v1));
                pk.z = __builtin_bit_cast(unsigned short, f2b(v2));
                pk.w = __builtin_bit_cast(unsigned short, f2b(v3));
                long byte = ((long)pixidx * 128 + oc0 * 2) ^ psw;
                *(ushort4*)((char*)lin + byte) = pk;
            }
        }
    }
    __syncthreads();
    bf16* outt = outp + (((long)b * Hc + y0) * Wc + x0) * 64;
    #pragma unroll
    for (int off = t * 16; off < TR * TC * 128; off += 4096) {
        int pix = off >> 7;
        int r = pix >> 5, c = pix & 31;
        long sb = (long)off ^ ((pix & 7) << 4);
        bf16x8 v = *(const bf16x8*)((const char*)lin + sb);
        *(bf16x8*)((char*)outt + ((long)(r * Wc + c)) * 128 + (off & 127)) = v;
    }
}

// ---------------- conv0: 2->64 @256, zf f32 NHWC direct -------------------
__global__ __launch_bounds__(256) void conv0_k(
    const float* __restrict__ zf, const bf16* __restrict__ wfb,
    bf16* __restrict__ outp)
{
    __shared__ float wsh[2][9][64];
    __shared__ float bsh[64];
    const int t = threadIdx.x;
    const int b = blockIdx.z;
    const long wb = (long)b * ODIM;
    for (int i = t; i < 1152; i += 256) {
        int oc = i / 18, r2 = i % 18, ic = r2 / 9, tap = r2 % 9;
        wsh[ic][tap][oc] = b2f(wfb[wb + i]);
    }
    if (t < 64) bsh[t] = b2f(wfb[wb + 591104 + t]);
    __syncthreads();
    const int pl = t >> 3, g = t & 7;
    const int pix = blockIdx.x * 32 + pl;
    const int y = pix >> 8, x = pix & 255;
    float acc[8];
    #pragma unroll
    for (int j = 0; j < 8; ++j) acc[j] = bsh[g * 8 + j];
    const float* zb = zf + (long)b * 131072;
    #pragma unroll
    for (int dy = 0; dy < 3; ++dy) {
        int yy = y + dy - 1;
        if ((unsigned)yy >= 256u) continue;
        #pragma unroll
        for (int dx = 0; dx < 3; ++dx) {
            int xx = x + dx - 1;
            if ((unsigned)xx >= 256u) continue;
            const float* p = zb + ((long)yy * 256 + xx) * 2;
            float v0 = p[0], v1 = p[1];
            int tap = dy * 3 + dx;
            #pragma unroll
            for (int j = 0; j < 8; ++j)
                acc[j] += v0 * wsh[0][tap][g*8+j] + v1 * wsh[1][tap][g*8+j];
        }
    }
    bf16x8 v;
    #pragma unroll
    for (int j = 0; j < 8; ++j) v[j] = (__bf16)fmaxf(acc[j], 0.f);
    *(bf16x8*)(outp + ((long)b * 65536 + pix) * 64 + g * 8) = v;
}

// ---------- final 1x1 conv (64->2) + residual + NHWC f32 store ------------
__global__ __launch_bounds__(256) void final_k(
    const bf16* __restrict__ X, const bf16* __restrict__ wfb,
    const float* __restrict__ zf, float* __restrict__ outp)
{
    __shared__ float wsh[128];
    __shared__ float bsh[2];
    const int t = threadIdx.x;
    const int i = blockIdx.x * 256 + t;
    const int pix = i & 65535;
    const int b = i >> 16;
    const long wb = (long)b * ODIM;
    if (t < 128) wsh[t] = b2f(wfb[wb + 590976 + t]);
    if (t < 2) bsh[t] = b2f(wfb[wb + 592000 + t]);
    __syncthreads();
    const bf16* p = X + ((long)b * 65536 + pix) * 64;
    float a0 = bsh[0], a1 = bsh[1];
    #pragma unroll
    for (int gq = 0; gq < 8; ++gq) {
        bf16x8 v = *(const bf16x8*)(p + gq * 8);
        #pragma unroll
        for (int j = 0; j < 8; ++j) {
            float f = (float)v[j];
            a0 += f * wsh[gq*8 + j];
            a1 += f * wsh[64 + gq*8 + j];
        }
    }
    long zi = ((long)b * 65536 + pix) * 2;
    outp[zi] = zf[zi] + a0;
    outp[zi + 1] = zf[zi + 1] + a1;
}

extern "C" void kernel_launch(void* const* d_in, const int* in_sizes, int n_in,
                              void* d_out, int out_size, void* d_ws, size_t ws_size,
                              hipStream_t stream)
{
    (void)in_sizes; (void)n_in; (void)out_size; (void)ws_size;
    const float* zf = (const float*)d_in[0];
    const float* hp = (const float*)d_in[2];
    const float* W1 = (const float*)d_in[3];
    const float* b1 = (const float*)d_in[4];
    const float* W2 = (const float*)d_in[5];
    const float* b2 = (const float*)d_in[6];
    const float* Wo = (const float*)d_in[7];
    const float* bo = (const float*)d_in[8];
    float* out = (float*)d_out;

    // ---- workspace carve (~218 MB) ----
    char* base = (char*)d_ws;
    float* h2   = (float*)base;  base += 1024;
    float* part = (float*)base;  base += 18504L * 4 + 32;
    bf16* wfb   = (bf16*)base;   base += 4736016L * 2 + 32;   // tanh weights (flat)
    bf16* WREP  = (bf16*)base;   base += 4718592L * 2;        // fragment-ordered weights
    bf16* Y256  = (bf16*)base;   base += 33554432L * 2;       // 8*256*256*64
    bf16* C1s   = (bf16*)base;   base += 33554432L * 2;
    bf16* D128a = (bf16*)base;   base += 8388608L * 2;        // 8*128*128*64
    bf16* C2s   = (bf16*)base;   base += 8388608L * 2;
    bf16* X128  = (bf16*)base;   base += 8388608L * 2;
    bf16* E64a  = (bf16*)base;   base += 2097152L * 2;        // 8*64*64*64
    bf16* C3s   = (bf16*)base;   base += 2097152L * 2;
    bf16* X64   = (bf16*)base;   base += 2097152L * 2;
    bf16* F32a  = (bf16*)base;   base += 524288L * 2;         // 8*32*32*64
    bf16* C4    = (bf16*)base;   base += 524288L * 2;

    hyper_h<<<1, 256, 0, stream>>>(hp, W1, b1, W2, b2, h2);
    const int ngb = (int)((ODIM + 255) / 256);   // 2313
    genw<<<ngb, 256, 0, stream>>>(Wo, bo, h2, wfb, part);
    l1_reduce<<<1, 256, 0, stream>>>(part, ngb, out + 1048576);

    const int BB = 591104;
    const long R1=0, R2=36864, R3=73728, R4=110592, R5=147456, R6=184320,
               R7=221184, R8=258048, R9=331776, R10=368640, R11=442368,
               R12=479232, R13=552960;

    repack_all<<<dim3(2304, 8), 256, 0, stream>>>(wfb, WREP);

    conv0_k<<<dim3(2048, 1, 8), 256, 0, stream>>>(zf, wfb, Y256);

    // encoder  (tile: TR=16, TC=32 -> 512 px/block, 76.5KB LDS, 2 blk/CU)
    conv_mfma<0><<<dim3(8,16,8),  256, 0, stream>>>(Y256, nullptr, 256,256, WREP, R1,  wfb, BB+64,  C1s);
    conv_mfma<1><<<dim3(4,8,8),   256, 0, stream>>>(C1s,  nullptr, 128,128, WREP, R2,  wfb, BB+128, D128a);
    conv_mfma<0><<<dim3(4,8,8),   256, 0, stream>>>(D128a,nullptr, 128,128, WREP, R3,  wfb, BB+192, C2s);
    conv_mfma<1><<<dim3(2,4,8),   256, 0, stream>>>(C2s,  nullptr, 64,64,   WREP, R4,  wfb, BB+256, E64a);
    conv_mfma<0><<<dim3(2,4,8),   256, 0, stream>>>(E64a, nullptr, 64,64,   WREP, R5,  wfb, BB+320, C3s);
    conv_mfma<1><<<dim3(1,2,8),   256, 0, stream>>>(C3s,  nullptr, 32,32,   WREP, R6,  wfb, BB+384, F32a);
    conv_mfma<0><<<dim3(1,2,8),   256, 0, stream>>>(F32a, nullptr, 32,32,   WREP, R7,  wfb, BB+448, C4);
    // decoder (UP fused into staging; concat = 2nd K-pass)
    conv_mfma<2><<<dim3(2,4,8),   256, 0, stream>>>(C4,   C3s, 64,64,   WREP, R8,  wfb, BB+512, E64a);
    conv_mfma<0><<<dim3(2,4,8),   256, 0, stream>>>(E64a, nullptr, 64,64, WREP, R9,  wfb, BB+576, X64);
    conv_mfma<2><<<dim3(4,8,8),   256, 0, stream>>>(X64,  C2s, 128,128, WREP, R10, wfb, BB+640, D128a);
    conv_mfma<0><<<dim3(4,8,8),   256, 0, stream>>>(D128a,nullptr,128,128, WREP, R11, wfb, BB+704, X128);
    conv_mfma<2><<<dim3(8,16,8),  256, 0, stream>>>(X128, C1s, 256,256, WREP, R12, wfb, BB+768, Y256);
    conv_mfma<0><<<dim3(8,16,8),  256, 0, stream>>>(Y256, nullptr,256,256, WREP, R13, wfb, BB+832, C1s);

    final_k<<<dim3(2048), 256, 0, stream>>>(C1s, wfb, zf, out);
}

// Round 11
// 624.043 us; speedup vs baseline: 1.2222x; 1.2222x over previous
//
#include <hip/hip_runtime.h>
#include <hip/hip_bf16.h>
#include <math.h>

#define ODIM 592002L
#define WRB  589824L
#define NB 8

typedef __hip_bfloat16 bf16;
typedef __bf16  bf16x8 __attribute__((ext_vector_type(8)));
typedef float   f32x16 __attribute__((ext_vector_type(16)));
typedef short   s16x8  __attribute__((ext_vector_type(8)));

__device__ __forceinline__ float b2f(bf16 x) { return __bfloat162float(x); }
__device__ __forceinline__ bf16 f2b(float x) { return __float2bfloat16(x); }
__device__ __forceinline__ bf16x8 bzero() { return __builtin_bit_cast(bf16x8, (s16x8)0); }

// ---------------- hypernet: h2 = (hp*W1^T + b1) @ W2^T + b2 ----------------
__global__ __launch_bounds__(256) void hyper_h(
    const float* __restrict__ hp, const float* __restrict__ W1,
    const float* __restrict__ b1, const float* __restrict__ W2,
    const float* __restrict__ b2, float* __restrict__ h2out)
{
    __shared__ float h1[NB][32];
    int t = threadIdx.x;
    int b = t >> 5, i = t & 31;
    h1[b][i] = hp[b] * W1[i] + b1[i];
    __syncthreads();
    float acc = b2[i];
    #pragma unroll
    for (int j = 0; j < 32; ++j) acc += h1[b][j] * W2[i * 32 + j];
    h2out[b * 32 + i] = acc;
}

// ------- w = tanh(h2 @ Wo^T + bo) -> bf16, + per-block |w| partials (f32) --
__global__ __launch_bounds__(256) void genw(
    const float* __restrict__ Wo, const float* __restrict__ bo,
    const float* __restrict__ h2, bf16* __restrict__ wfb,
    float* __restrict__ part)
{
    __shared__ float h2s[256];
    __shared__ float red[256];
    int t = threadIdx.x;
    h2s[t] = h2[t];
    __syncthreads();
    long o = (long)blockIdx.x * 256 + t;
    float absacc[NB];
    #pragma unroll
    for (int b = 0; b < NB; ++b) absacc[b] = 0.f;
    if (o < ODIM) {
        float row[32];
        const float4* wp = (const float4*)(Wo + o * 32);
        #pragma unroll
        for (int q = 0; q < 8; ++q) {
            float4 v = wp[q];
            row[q*4+0] = v.x; row[q*4+1] = v.y; row[q*4+2] = v.z; row[q*4+3] = v.w;
        }
        float bias = bo[o];
        #pragma unroll
        for (int b = 0; b < NB; ++b) {
            float acc = bias;
            #pragma unroll
            for (int k = 0; k < 32; ++k) acc += h2s[b*32+k] * row[k];
            float w = tanhf(acc);
            wfb[(long)b * ODIM + o] = f2b(w);
            absacc[b] = fabsf(w);
        }
    }
    for (int b = 0; b < NB; ++b) {
        red[t] = absacc[b];
        __syncthreads();
        for (int s = 128; s > 0; s >>= 1) {
            if (t < s) red[t] += red[t + s];
            __syncthreads();
        }
        if (t == 0) part[(long)blockIdx.x * NB + b] = red[0];
        __syncthreads();
    }
}

__global__ __launch_bounds__(256) void l1_reduce(
    const float* __restrict__ part, int nblk, float* __restrict__ outp)
{
    __shared__ float red[256];
    int t = threadIdx.x; int b = t & 7, ch = t >> 3;
    float s = 0.f;
    for (int i = ch; i < nblk; i += 32) s += part[(long)i * 8 + b];
    red[t] = s;
    __syncthreads();
    for (int st = 128; st >= 8; st >>= 1) {
        if (t < st) red[t] += red[t + st];
        __syncthreads();
    }
    if (t < 8) outp[t] = red[t];
}

// ---- repack ALL layers into per-lane MFMA fragment order (one launch) ----
// frag fid = ((pass*9 + tap)*4 + k4)*2 + oc_half ; then [lane][8].
__global__ __launch_bounds__(256) void repack_all(
    const bf16* __restrict__ wfb, bf16* __restrict__ wr)
{
    int i = blockIdx.x * 256 + threadIdx.x;   // 0..WRB-1
    int b = blockIdx.y;
    if (i >= (int)WRB) return;
    int roff, koff, dual = 0;
    if      (i < 36864)  { roff = 0;      koff = 1152;  }
    else if (i < 73728)  { roff = 36864;  koff = 38016; }
    else if (i < 110592) { roff = 73728;  koff = 74880; }
    else if (i < 147456) { roff = 110592; koff = 111744;}
    else if (i < 184320) { roff = 147456; koff = 148608;}
    else if (i < 221184) { roff = 184320; koff = 185472;}
    else if (i < 258048) { roff = 221184; koff = 222336;}
    else if (i < 331776) { roff = 258048; koff = 259200; dual = 1; }
    else if (i < 368640) { roff = 331776; koff = 332928;}
    else if (i < 442368) { roff = 368640; koff = 369792; dual = 1; }
    else if (i < 479232) { roff = 442368; koff = 443520;}
    else if (i < 552960) { roff = 479232; koff = 480384; dual = 1; }
    else                 { roff = 552960; koff = 554112;}
    int li = i - roff;
    int Cinfull = dual ? 128 : 64;
    int fid = li >> 9;
    int lane = (li >> 3) & 63;
    int j = li & 7;
    int h = fid & 1;
    int kk = fid >> 1;
    int k4 = kk & 3;
    int tapq = kk >> 2;
    int tap = tapq % 9;
    int pass = tapq / 9;
    int oc = h * 32 + (lane & 31);
    int icf = pass * 64 + k4 * 16 + (lane >> 5) * 8 + j;
    wr[(long)b * WRB + i] =
        wfb[(long)b * ODIM + koff + ((long)oc * Cinfull + icf) * 9 + tap];
}

// ---------------- LDS staging: PLAIN(0) / POOL(1) / UP2(2) ----------------
template<int TR, int TC, int MODE>
__device__ __forceinline__ void stage_tile(
    const bf16* __restrict__ src, int Hc, int Wc, int y0, int x0,
    bf16* lin, int t)
{
    const int XL = TC + 2;
    const int total = (TR + 2) * XL * 8;
    for (int idx = t; idx < total; idx += 256) {
        const int g = idx & 7;
        const int rem = idx >> 3;
        const int xl = rem % XL;
        const int gy = y0 + rem / XL - 1, gx = x0 + xl - 1;
        bf16x8 v = bzero();
        if ((unsigned)gy < (unsigned)Hc && (unsigned)gx < (unsigned)Wc) {
            if constexpr (MODE == 0) {
                v = *(const bf16x8*)(src + (((long)gy * Wc) + gx) * 64 + g * 8);
            } else if constexpr (MODE == 1) {
                const int Ws = Wc * 2;
                const bf16* p = src + (((long)(gy*2) * Ws) + gx*2) * 64 + g * 8;
                bf16x8 aa = *(const bf16x8*)p;
                bf16x8 bb = *(const bf16x8*)(p + 64);
                bf16x8 cc = *(const bf16x8*)(p + (long)Ws * 64);
                bf16x8 dd = *(const bf16x8*)(p + (long)Ws * 64 + 64);
                #pragma unroll
                for (int j = 0; j < 8; ++j) {
                    float m = fmaxf(fmaxf((float)aa[j], (float)bb[j]),
                                    fmaxf((float)cc[j], (float)dd[j]));
                    v[j] = (__bf16)m;
                }
            } else {
                const int Hs = Hc >> 1, Ws = Wc >> 1;
                const float sy = (float)(Hs - 1) / (float)(Hc - 1);
                const float sx = (float)(Ws - 1) / (float)(Wc - 1);
                float ys = gy * sy, xs = gx * sx;
                int yy0 = (int)ys, xx0 = (int)xs;
                int yy1 = min(yy0 + 1, Hs - 1), xx1 = min(xx0 + 1, Ws - 1);
                float wy = ys - (float)yy0, wx = xs - (float)xx0;
                bf16x8 q00 = *(const bf16x8*)(src + ((long)yy0*Ws + xx0)*64 + g*8);
                bf16x8 q01 = *(const bf16x8*)(src + ((long)yy0*Ws + xx1)*64 + g*8);
                bf16x8 q10 = *(const bf16x8*)(src + ((long)yy1*Ws + xx0)*64 + g*8);
                bf16x8 q11 = *(const bf16x8*)(src + ((long)yy1*Ws + xx1)*64 + g*8);
                #pragma unroll
                for (int j = 0; j < 8; ++j) {
                    float r0 = (float)q00[j]*(1.f-wx) + (float)q01[j]*wx;
                    float r1 = (float)q10[j]*(1.f-wx) + (float)q11[j]*wx;
                    v[j] = (__bf16)(r0*(1.f-wy) + r1*wy);
                }
            }
        }
        long byte = (((long)rem) * 128 + g * 16) ^ ((xl & 7) << 4);
        *(bf16x8*)((char*)lin + byte) = v;
    }
}

// ---------------- MFMA implicit-GEMM 3x3 conv, 64 oc, NHWC bf16 -----------
// Tile TR=8 x TC=32 = 256 px (round-5 proven shell, (256,3), no spill).
// NEW: wave w owns ADJACENT rows {2w, 2w+1}; per (k4,dxi) read 4 staged rows
// once and reuse across the 3 dy taps -> 4 ds_reads feed 12 MFMAs (1:3 vs
// round-5 1:2) -> LDS-pipe cap rises 33%->50% MfmaUtil. acc stays [2][2].
template<int MODE>
__global__ __launch_bounds__(256, 3) void conv_mfma(
    const bf16* __restrict__ src1, const bf16* __restrict__ src2,
    int Hc, int Wc,
    const bf16* __restrict__ wr, long roff,
    const bf16* __restrict__ wfb, int boff,
    bf16* __restrict__ outp)
{
    const int TR = 8, TC = 32, XL = TC + 2;
    __shared__ bf16 lin[(TR + 2) * XL * 64];     // 43520 B
    __shared__ float biasf[64];
    const int t = threadIdx.x;
    const int lane = t & 63;
    const int w = t >> 6;
    const int b = blockIdx.z;
    const int y0 = blockIdx.y * TR;
    const int x0 = blockIdx.x * TC;
    const int lx = lane & 31;

    f32x16 acc00 = {}, acc01 = {}, acc10 = {}, acc11 = {};

    const bf16* wl = wr + (long)b * WRB + roff;
    if (t < 64) biasf[t] = b2f(wfb[(long)b * ODIM + boff + t]);

    const int icbl = (lane >> 5) * 16;
    const int wrow = 2 * w;     // output rows 2w, 2w+1

    auto kpass = [&](int p) {
        #pragma unroll
        for (int k4 = 0; k4 < 4; ++k4) {
            #pragma unroll
            for (int dxi = 0; dxi < 3; ++dxi) {
                const int xl = lx + dxi;
                const int co = xl * 128 + ((k4 * 32 + icbl) ^ ((xl & 7) << 4));
                bf16x8 bfr[4];
                #pragma unroll
                for (int rr = 0; rr < 4; ++rr)
                    bfr[rr] = *(const bf16x8*)((const char*)lin + (wrow + rr) * (XL * 128) + co);
                #pragma unroll
                for (int dy = 0; dy < 3; ++dy) {
                    const int fid = ((p * 9 + dy * 3 + dxi) * 4 + k4) * 2;
                    const bf16* pk = wl + ((long)fid << 9) + (lane << 3);
                    bf16x8 a0 = *(const bf16x8*)pk;
                    bf16x8 a1 = *(const bf16x8*)(pk + 512);
                    acc00 = __builtin_amdgcn_mfma_f32_32x32x16_bf16(a0, bfr[dy],     acc00, 0, 0, 0);
                    acc01 = __builtin_amdgcn_mfma_f32_32x32x16_bf16(a1, bfr[dy],     acc01, 0, 0, 0);
                    acc10 = __builtin_amdgcn_mfma_f32_32x32x16_bf16(a0, bfr[dy + 1], acc10, 0, 0, 0);
                    acc11 = __builtin_amdgcn_mfma_f32_32x32x16_bf16(a1, bfr[dy + 1], acc11, 0, 0, 0);
                }
            }
        }
    };

    stage_tile<TR, TC, MODE>(src1, Hc, Wc, y0, x0, lin, t);
    __syncthreads();
    kpass(0);
    if (src2) {
        __syncthreads();
        stage_tile<TR, TC, 0>(src2, Hc, Wc, y0, x0, lin, t);
        __syncthreads();
        kpass(1);
    }

    // ---- epilogue: acc -> LDS [pix][oc] (swizzled) -> coalesced store ----
    __syncthreads();
    #pragma unroll
    for (int r = 0; r < 2; ++r) {
        const int pixidx = (wrow + r) * TC + lx;
        const int psw = (pixidx & 7) << 4;
        #pragma unroll
        for (int ocs = 0; ocs < 2; ++ocs) {
            const f32x16& A = r ? (ocs ? acc11 : acc10) : (ocs ? acc01 : acc00);
            #pragma unroll
            for (int q = 0; q < 4; ++q) {
                const int oc0 = ocs * 32 + 8 * q + 4 * (lane >> 5);
                ushort4 pk;
                float v0 = fmaxf(A[4*q+0] + biasf[oc0 + 0], 0.f);
                float v1 = fmaxf(A[4*q+1] + biasf[oc0 + 1], 0.f);
                float v2 = fmaxf(A[4*q+2] + biasf[oc0 + 2], 0.f);
                float v3 = fmaxf(A[4*q+3] + biasf[oc0 + 3], 0.f);
                pk.x = __builtin_bit_cast(unsigned short, f2b(v0));
                pk.y = __builtin_bit_cast(unsigned short, f2b(v1));
                pk.z = __builtin_bit_cast(unsigned short, f2b(v2));
                pk.w = __builtin_bit_cast(unsigned short, f2b(v3));
                long byte = ((long)pixidx * 128 + oc0 * 2) ^ psw;
                *(ushort4*)((char*)lin + byte) = pk;
            }
        }
    }
    __syncthreads();
    bf16* outt = outp + (((long)b * Hc + y0) * Wc + x0) * 64;
    #pragma unroll
    for (int off = t * 16; off < TR * TC * 128; off += 4096) {
        int pix = off >> 7;
        int r = pix >> 5, c = pix & 31;
        long sb = (long)off ^ ((pix & 7) << 4);
        bf16x8 v = *(const bf16x8*)((const char*)lin + sb);
        *(bf16x8*)((char*)outt + ((long)(r * Wc + c)) * 128 + (off & 127)) = v;
    }
}

// ---------------- conv0: 2->64 @256, zf f32 NHWC direct -------------------
__global__ __launch_bounds__(256) void conv0_k(
    const float* __restrict__ zf, const bf16* __restrict__ wfb,
    bf16* __restrict__ outp)
{
    __shared__ float wsh[2][9][64];
    __shared__ float bsh[64];
    const int t = threadIdx.x;
    const int b = blockIdx.z;
    const long wb = (long)b * ODIM;
    for (int i = t; i < 1152; i += 256) {
        int oc = i / 18, r2 = i % 18, ic = r2 / 9, tap = r2 % 9;
        wsh[ic][tap][oc] = b2f(wfb[wb + i]);
    }
    if (t < 64) bsh[t] = b2f(wfb[wb + 591104 + t]);
    __syncthreads();
    const int pl = t >> 3, g = t & 7;
    const int pix = blockIdx.x * 32 + pl;
    const int y = pix >> 8, x = pix & 255;
    float acc[8];
    #pragma unroll
    for (int j = 0; j < 8; ++j) acc[j] = bsh[g * 8 + j];
    const float* zb = zf + (long)b * 131072;
    #pragma unroll
    for (int dy = 0; dy < 3; ++dy) {
        int yy = y + dy - 1;
        if ((unsigned)yy >= 256u) continue;
        #pragma unroll
        for (int dx = 0; dx < 3; ++dx) {
            int xx = x + dx - 1;
            if ((unsigned)xx >= 256u) continue;
            const float* p = zb + ((long)yy * 256 + xx) * 2;
            float v0 = p[0], v1 = p[1];
            int tap = dy * 3 + dx;
            #pragma unroll
            for (int j = 0; j < 8; ++j)
                acc[j] += v0 * wsh[0][tap][g*8+j] + v1 * wsh[1][tap][g*8+j];
        }
    }
    bf16x8 v;
    #pragma unroll
    for (int j = 0; j < 8; ++j) v[j] = (__bf16)fmaxf(acc[j], 0.f);
    *(bf16x8*)(outp + ((long)b * 65536 + pix) * 64 + g * 8) = v;
}

// ---------- final 1x1 conv (64->2) + residual + NHWC f32 store ------------
__global__ __launch_bounds__(256) void final_k(
    const bf16* __restrict__ X, const bf16* __restrict__ wfb,
    const float* __restrict__ zf, float* __restrict__ outp)
{
    __shared__ float wsh[128];
    __shared__ float bsh[2];
    const int t = threadIdx.x;
    const int i = blockIdx.x * 256 + t;
    const int pix = i & 65535;
    const int b = i >> 16;
    const long wb = (long)b * ODIM;
    if (t < 128) wsh[t] = b2f(wfb[wb + 590976 + t]);
    if (t < 2) bsh[t] = b2f(wfb[wb + 592000 + t]);
    __syncthreads();
    const bf16* p = X + ((long)b * 65536 + pix) * 64;
    float a0 = bsh[0], a1 = bsh[1];
    #pragma unroll
    for (int gq = 0; gq < 8; ++gq) {
        bf16x8 v = *(const bf16x8*)(p + gq * 8);
        #pragma unroll
        for (int j = 0; j < 8; ++j) {
            float f = (float)v[j];
            a0 += f * wsh[gq*8 + j];
            a1 += f * wsh[64 + gq*8 + j];
        }
    }
    long zi = ((long)b * 65536 + pix) * 2;
    outp[zi] = zf[zi] + a0;
    outp[zi + 1] = zf[zi + 1] + a1;
}

extern "C" void kernel_launch(void* const* d_in, const int* in_sizes, int n_in,
                              void* d_out, int out_size, void* d_ws, size_t ws_size,
                              hipStream_t stream)
{
    (void)in_sizes; (void)n_in; (void)out_size; (void)ws_size;
    const float* zf = (const float*)d_in[0];
    const float* hp = (const float*)d_in[2];
    const float* W1 = (const float*)d_in[3];
    const float* b1 = (const float*)d_in[4];
    const float* W2 = (const float*)d_in[5];
    const float* b2 = (const float*)d_in[6];
    const float* Wo = (const float*)d_in[7];
    const float* bo = (const float*)d_in[8];
    float* out = (float*)d_out;

    // ---- workspace carve (~218 MB) ----
    char* base = (char*)d_ws;
    float* h2   = (float*)base;  base += 1024;
    float* part = (float*)base;  base += 18504L * 4 + 32;
    bf16* wfb   = (bf16*)base;   base += 4736016L * 2 + 32;   // tanh weights (flat)
    bf16* WREP  = (bf16*)base;   base += 4718592L * 2;        // fragment-ordered weights
    bf16* Y256  = (bf16*)base;   base += 33554432L * 2;       // 8*256*256*64
    bf16* C1s   = (bf16*)base;   base += 33554432L * 2;
    bf16* D128a = (bf16*)base;   base += 8388608L * 2;        // 8*128*128*64
    bf16* C2s   = (bf16*)base;   base += 8388608L * 2;
    bf16* X128  = (bf16*)base;   base += 8388608L * 2;
    bf16* E64a  = (bf16*)base;   base += 2097152L * 2;        // 8*64*64*64
    bf16* C3s   = (bf16*)base;   base += 2097152L * 2;
    bf16* X64   = (bf16*)base;   base += 2097152L * 2;
    bf16* F32a  = (bf16*)base;   base += 524288L * 2;         // 8*32*32*64
    bf16* C4    = (bf16*)base;   base += 524288L * 2;

    hyper_h<<<1, 256, 0, stream>>>(hp, W1, b1, W2, b2, h2);
    const int ngb = (int)((ODIM + 255) / 256);   // 2313
    genw<<<ngb, 256, 0, stream>>>(Wo, bo, h2, wfb, part);
    l1_reduce<<<1, 256, 0, stream>>>(part, ngb, out + 1048576);

    const int BB = 591104;
    const long R1=0, R2=36864, R3=73728, R4=110592, R5=147456, R6=184320,
               R7=221184, R8=258048, R9=331776, R10=368640, R11=442368,
               R12=479232, R13=552960;

    repack_all<<<dim3(2304, 8), 256, 0, stream>>>(wfb, WREP);

    conv0_k<<<dim3(2048, 1, 8), 256, 0, stream>>>(zf, wfb, Y256);

    // encoder  (tile: TR=8, TC=32 -> 256 px/block, 43.5KB LDS, 3 blk/CU)
    conv_mfma<0><<<dim3(8,32,8),  256, 0, stream>>>(Y256, nullptr, 256,256, WREP, R1,  wfb, BB+64,  C1s);
    conv_mfma<1><<<dim3(4,16,8),  256, 0, stream>>>(C1s,  nullptr, 128,128, WREP, R2,  wfb, BB+128, D128a);
    conv_mfma<0><<<dim3(4,16,8),  256, 0, stream>>>(D128a,nullptr, 128,128, WREP, R3,  wfb, BB+192, C2s);
    conv_mfma<1><<<dim3(2,8,8),   256, 0, stream>>>(C2s,  nullptr, 64,64,   WREP, R4,  wfb, BB+256, E64a);
    conv_mfma<0><<<dim3(2,8,8),   256, 0, stream>>>(E64a, nullptr, 64,64,   WREP, R5,  wfb, BB+320, C3s);
    conv_mfma<1><<<dim3(1,4,8),   256, 0, stream>>>(C3s,  nullptr, 32,32,   WREP, R6,  wfb, BB+384, F32a);
    conv_mfma<0><<<dim3(1,4,8),   256, 0, stream>>>(F32a, nullptr, 32,32,   WREP, R7,  wfb, BB+448, C4);
    // decoder (UP fused into staging; concat = 2nd K-pass)
    conv_mfma<2><<<dim3(2,8,8),   256, 0, stream>>>(C4,   C3s, 64,64,   WREP, R8,  wfb, BB+512, E64a);
    conv_mfma<0><<<dim3(2,8,8),   256, 0, stream>>>(E64a, nullptr, 64,64, WREP, R9,  wfb, BB+576, X64);
    conv_mfma<2><<<dim3(4,16,8),  256, 0, stream>>>(X64,  C2s, 128,128, WREP, R10, wfb, BB+640, D128a);
    conv_mfma<0><<<dim3(4,16,8),  256, 0, stream>>>(D128a,nullptr,128,128, WREP, R11, wfb, BB+704, X128);
    conv_mfma<2><<<dim3(8,32,8),  256, 0, stream>>>(X128, C1s, 256,256, WREP, R12, wfb, BB+768, Y256);
    conv_mfma<0><<<dim3(8,32,8),  256, 0, stream>>>(Y256, nullptr,256,256, WREP, R13, wfb, BB+832, C1s);

    final_k<<<dim3(2048), 256, 0, stream>>>(C1s, wfb, zf, out);
}

// Round 12
// 556.062 us; speedup vs baseline: 1.3716x; 1.1223x over previous
//
#include <hip/hip_runtime.h>
#include <hip/hip_bf16.h>
#include <math.h>

#define ODIM 592002L
#define WRB  589824L
#define NB 8

typedef __hip_bfloat16 bf16;
typedef __bf16  bf16x8 __attribute__((ext_vector_type(8)));
typedef float   f32x16 __attribute__((ext_vector_type(16)));
typedef short   s16x8  __attribute__((ext_vector_type(8)));

__device__ __forceinline__ float b2f(bf16 x) { return __bfloat162float(x); }
__device__ __forceinline__ bf16 f2b(float x) { return __float2bfloat16(x); }
__device__ __forceinline__ bf16x8 bzero() { return __builtin_bit_cast(bf16x8, (s16x8)0); }

// ---------------- hypernet: h2 = (hp*W1^T + b1) @ W2^T + b2 ----------------
__global__ __launch_bounds__(256) void hyper_h(
    const float* __restrict__ hp, const float* __restrict__ W1,
    const float* __restrict__ b1, const float* __restrict__ W2,
    const float* __restrict__ b2, float* __restrict__ h2out)
{
    __shared__ float h1[NB][32];
    int t = threadIdx.x;
    int b = t >> 5, i = t & 31;
    h1[b][i] = hp[b] * W1[i] + b1[i];
    __syncthreads();
    float acc = b2[i];
    #pragma unroll
    for (int j = 0; j < 32; ++j) acc += h1[b][j] * W2[i * 32 + j];
    h2out[b * 32 + i] = acc;
}

// ------- w = tanh(h2 @ Wo^T + bo) -> bf16, + per-block |w| partials (f32) --
__global__ __launch_bounds__(256) void genw(
    const float* __restrict__ Wo, const float* __restrict__ bo,
    const float* __restrict__ h2, bf16* __restrict__ wfb,
    float* __restrict__ part)
{
    __shared__ float h2s[256];
    __shared__ float red[256];
    int t = threadIdx.x;
    h2s[t] = h2[t];
    __syncthreads();
    long o = (long)blockIdx.x * 256 + t;
    float absacc[NB];
    #pragma unroll
    for (int b = 0; b < NB; ++b) absacc[b] = 0.f;
    if (o < ODIM) {
        float row[32];
        const float4* wp = (const float4*)(Wo + o * 32);
        #pragma unroll
        for (int q = 0; q < 8; ++q) {
            float4 v = wp[q];
            row[q*4+0] = v.x; row[q*4+1] = v.y; row[q*4+2] = v.z; row[q*4+3] = v.w;
        }
        float bias = bo[o];
        #pragma unroll
        for (int b = 0; b < NB; ++b) {
            float acc = bias;
            #pragma unroll
            for (int k = 0; k < 32; ++k) acc += h2s[b*32+k] * row[k];
            float w = tanhf(acc);
            wfb[(long)b * ODIM + o] = f2b(w);
            absacc[b] = fabsf(w);
        }
    }
    for (int b = 0; b < NB; ++b) {
        red[t] = absacc[b];
        __syncthreads();
        for (int s = 128; s > 0; s >>= 1) {
            if (t < s) red[t] += red[t + s];
            __syncthreads();
        }
        if (t == 0) part[(long)blockIdx.x * NB + b] = red[0];
        __syncthreads();
    }
}

__global__ __launch_bounds__(256) void l1_reduce(
    const float* __restrict__ part, int nblk, float* __restrict__ outp)
{
    __shared__ float red[256];
    int t = threadIdx.x; int b = t & 7, ch = t >> 3;
    float s = 0.f;
    for (int i = ch; i < nblk; i += 32) s += part[(long)i * 8 + b];
    red[t] = s;
    __syncthreads();
    for (int st = 128; st >= 8; st >>= 1) {
        if (t < st) red[t] += red[t + st];
        __syncthreads();
    }
    if (t < 8) outp[t] = red[t];
}

// ---- repack ALL layers into per-lane MFMA fragment order (one launch) ----
// frag fid = ((pass*9 + tap)*4 + k4)*2 + oc_half ; then [lane][8].
__global__ __launch_bounds__(256) void repack_all(
    const bf16* __restrict__ wfb, bf16* __restrict__ wr)
{
    int i = blockIdx.x * 256 + threadIdx.x;   // 0..WRB-1
    int b = blockIdx.y;
    if (i >= (int)WRB) return;
    int roff, koff, dual = 0;
    if      (i < 36864)  { roff = 0;      koff = 1152;  }
    else if (i < 73728)  { roff = 36864;  koff = 38016; }
    else if (i < 110592) { roff = 73728;  koff = 74880; }
    else if (i < 147456) { roff = 110592; koff = 111744;}
    else if (i < 184320) { roff = 147456; koff = 148608;}
    else if (i < 221184) { roff = 184320; koff = 185472;}
    else if (i < 258048) { roff = 221184; koff = 222336;}
    else if (i < 331776) { roff = 258048; koff = 259200; dual = 1; }
    else if (i < 368640) { roff = 331776; koff = 332928;}
    else if (i < 442368) { roff = 368640; koff = 369792; dual = 1; }
    else if (i < 479232) { roff = 442368; koff = 443520;}
    else if (i < 552960) { roff = 479232; koff = 480384; dual = 1; }
    else                 { roff = 552960; koff = 554112;}
    int li = i - roff;
    int Cinfull = dual ? 128 : 64;
    int fid = li >> 9;
    int lane = (li >> 3) & 63;
    int j = li & 7;
    int h = fid & 1;
    int kk = fid >> 1;
    int k4 = kk & 3;
    int tapq = kk >> 2;
    int tap = tapq % 9;
    int pass = tapq / 9;
    int oc = h * 32 + (lane & 31);
    int icf = pass * 64 + k4 * 16 + (lane >> 5) * 8 + j;
    wr[(long)b * WRB + i] =
        wfb[(long)b * ODIM + koff + ((long)oc * Cinfull + icf) * 9 + tap];
}

// ---------------- LDS staging: PLAIN(0) / POOL(1) / UP2(2) ----------------
template<int TR, int TC, int MODE>
__device__ __forceinline__ void stage_tile(
    const bf16* __restrict__ src, int Hc, int Wc, int y0, int x0,
    bf16* lin, int t)
{
    const int XL = TC + 2;
    const int total = (TR + 2) * XL * 8;
    for (int idx = t; idx < total; idx += 256) {
        const int g = idx & 7;
        const int rem = idx >> 3;
        const int xl = rem % XL;
        const int gy = y0 + rem / XL - 1, gx = x0 + xl - 1;
        bf16x8 v = bzero();
        if ((unsigned)gy < (unsigned)Hc && (unsigned)gx < (unsigned)Wc) {
            if constexpr (MODE == 0) {
                v = *(const bf16x8*)(src + (((long)gy * Wc) + gx) * 64 + g * 8);
            } else if constexpr (MODE == 1) {
                const int Ws = Wc * 2;
                const bf16* p = src + (((long)(gy*2) * Ws) + gx*2) * 64 + g * 8;
                bf16x8 aa = *(const bf16x8*)p;
                bf16x8 bb = *(const bf16x8*)(p + 64);
                bf16x8 cc = *(const bf16x8*)(p + (long)Ws * 64);
                bf16x8 dd = *(const bf16x8*)(p + (long)Ws * 64 + 64);
                #pragma unroll
                for (int j = 0; j < 8; ++j) {
                    float m = fmaxf(fmaxf((float)aa[j], (float)bb[j]),
                                    fmaxf((float)cc[j], (float)dd[j]));
                    v[j] = (__bf16)m;
                }
            } else {
                const int Hs = Hc >> 1, Ws = Wc >> 1;
                const float sy = (float)(Hs - 1) / (float)(Hc - 1);
                const float sx = (float)(Ws - 1) / (float)(Wc - 1);
                float ys = gy * sy, xs = gx * sx;
                int yy0 = (int)ys, xx0 = (int)xs;
                int yy1 = min(yy0 + 1, Hs - 1), xx1 = min(xx0 + 1, Ws - 1);
                float wy = ys - (float)yy0, wx = xs - (float)xx0;
                bf16x8 q00 = *(const bf16x8*)(src + ((long)yy0*Ws + xx0)*64 + g*8);
                bf16x8 q01 = *(const bf16x8*)(src + ((long)yy0*Ws + xx1)*64 + g*8);
                bf16x8 q10 = *(const bf16x8*)(src + ((long)yy1*Ws + xx0)*64 + g*8);
                bf16x8 q11 = *(const bf16x8*)(src + ((long)yy1*Ws + xx1)*64 + g*8);
                #pragma unroll
                for (int j = 0; j < 8; ++j) {
                    float r0 = (float)q00[j]*(1.f-wx) + (float)q01[j]*wx;
                    float r1 = (float)q10[j]*(1.f-wx) + (float)q11[j]*wx;
                    v[j] = (__bf16)(r0*(1.f-wy) + r1*wy);
                }
            }
        }
        long byte = (((long)rem) * 128 + g * 16) ^ ((xl & 7) << 4);
        *(bf16x8*)((char*)lin + byte) = v;
    }
}

// ---------------- MFMA implicit-GEMM 3x3 conv, 64 oc, NHWC bf16 -----------
// Tile TR=8 x TC=32 = 256 px, (256,3). NEW oc-split decomposition: wave w =
// (oc-half w&1) x (4-row group w>>1). Per (k4,dxi,dy): ONE A-frag load feeds
// FOUR MFMAs (4 adjacent rows) -> 0.25KB weight/MFMA (was 0.5) -> L2-bw cap
// rises 25%->~50%. acc = 4 x f32x16 (64 AGPR) + bfr[6] ~= round-11's proven
// 84-VGPR profile (no spill).
template<int MODE>
__global__ __launch_bounds__(256, 3) void conv_mfma(
    const bf16* __restrict__ src1, const bf16* __restrict__ src2,
    int Hc, int Wc,
    const bf16* __restrict__ wr, long roff,
    const bf16* __restrict__ wfb, int boff,
    bf16* __restrict__ outp)
{
    const int TR = 8, TC = 32, XL = TC + 2;
    __shared__ bf16 lin[(TR + 2) * XL * 64];     // 43520 B
    __shared__ float biasf[64];
    const int t = threadIdx.x;
    const int lane = t & 63;
    const int w = t >> 6;
    const int half = w & 1;            // oc half
    const int wrow = (w >> 1) * 4;     // output rows wrow..wrow+3
    const int b = blockIdx.z;
    const int y0 = blockIdx.y * TR;
    const int x0 = blockIdx.x * TC;
    const int lx = lane & 31;

    f32x16 acc0 = {}, acc1 = {}, acc2 = {}, acc3 = {};

    const bf16* wl = wr + (long)b * WRB + roff;
    if (t < 64) biasf[t] = b2f(wfb[(long)b * ODIM + boff + t]);

    const int icbl = (lane >> 5) * 16;

    auto kpass = [&](int p) {
        #pragma unroll
        for (int k4 = 0; k4 < 4; ++k4) {
            #pragma unroll
            for (int dxi = 0; dxi < 3; ++dxi) {
                const int xl = lx + dxi;
                const int co = xl * 128 + ((k4 * 32 + icbl) ^ ((xl & 7) << 4));
                bf16x8 bfr[6];
                #pragma unroll
                for (int rr = 0; rr < 6; ++rr)
                    bfr[rr] = *(const bf16x8*)((const char*)lin + (wrow + rr) * (XL * 128) + co);
                #pragma unroll
                for (int dy = 0; dy < 3; ++dy) {
                    const int fid = ((p * 9 + dy * 3 + dxi) * 4 + k4) * 2 + half;
                    bf16x8 a0 = *(const bf16x8*)(wl + ((long)fid << 9) + (lane << 3));
                    acc0 = __builtin_amdgcn_mfma_f32_32x32x16_bf16(a0, bfr[dy + 0], acc0, 0, 0, 0);
                    acc1 = __builtin_amdgcn_mfma_f32_32x32x16_bf16(a0, bfr[dy + 1], acc1, 0, 0, 0);
                    acc2 = __builtin_amdgcn_mfma_f32_32x32x16_bf16(a0, bfr[dy + 2], acc2, 0, 0, 0);
                    acc3 = __builtin_amdgcn_mfma_f32_32x32x16_bf16(a0, bfr[dy + 3], acc3, 0, 0, 0);
                }
            }
        }
    };

    stage_tile<TR, TC, MODE>(src1, Hc, Wc, y0, x0, lin, t);
    __syncthreads();
    kpass(0);
    if (src2) {
        __syncthreads();
        stage_tile<TR, TC, 0>(src2, Hc, Wc, y0, x0, lin, t);
        __syncthreads();
        kpass(1);
    }

    // ---- epilogue: acc -> LDS [pix][oc] (swizzled) -> coalesced store ----
    __syncthreads();
    #pragma unroll
    for (int r = 0; r < 4; ++r) {
        const int pixidx = (wrow + r) * TC + lx;
        const int psw = (pixidx & 7) << 4;
        const f32x16& A = (r == 0) ? acc0 : (r == 1) ? acc1 : (r == 2) ? acc2 : acc3;
        #pragma unroll
        for (int q = 0; q < 4; ++q) {
            const int oc0 = half * 32 + 8 * q + 4 * (lane >> 5);
            ushort4 pk;
            float v0 = fmaxf(A[4*q+0] + biasf[oc0 + 0], 0.f);
            float v1 = fmaxf(A[4*q+1] + biasf[oc0 + 1], 0.f);
            float v2 = fmaxf(A[4*q+2] + biasf[oc0 + 2], 0.f);
            float v3 = fmaxf(A[4*q+3] + biasf[oc0 + 3], 0.f);
            pk.x = __builtin_bit_cast(unsigned short, f2b(v0));
            pk.y = __builtin_bit_cast(unsigned short, f2b(v1));
            pk.z = __builtin_bit_cast(unsigned short, f2b(v2));
            pk.w = __builtin_bit_cast(unsigned short, f2b(v3));
            long byte = ((long)pixidx * 128 + oc0 * 2) ^ psw;
            *(ushort4*)((char*)lin + byte) = pk;
        }
    }
    __syncthreads();
    bf16* outt = outp + (((long)b * Hc + y0) * Wc + x0) * 64;
    #pragma unroll
    for (int off = t * 16; off < TR * TC * 128; off += 4096) {
        int pix = off >> 7;
        int r = pix >> 5, c = pix & 31;
        long sb = (long)off ^ ((pix & 7) << 4);
        bf16x8 v = *(const bf16x8*)((const char*)lin + sb);
        *(bf16x8*)((char*)outt + ((long)(r * Wc + c)) * 128 + (off & 127)) = v;
    }
}

// ---------------- conv0: 2->64 @256, zf f32 NHWC direct -------------------
__global__ __launch_bounds__(256) void conv0_k(
    const float* __restrict__ zf, const bf16* __restrict__ wfb,
    bf16* __restrict__ outp)
{
    __shared__ float wsh[2][9][64];
    __shared__ float bsh[64];
    const int t = threadIdx.x;
    const int b = blockIdx.z;
    const long wb = (long)b * ODIM;
    for (int i = t; i < 1152; i += 256) {
        int oc = i / 18, r2 = i % 18, ic = r2 / 9, tap = r2 % 9;
        wsh[ic][tap][oc] = b2f(wfb[wb + i]);
    }
    if (t < 64) bsh[t] = b2f(wfb[wb + 591104 + t]);
    __syncthreads();
    const int pl = t >> 3, g = t & 7;
    const int pix = blockIdx.x * 32 + pl;
    const int y = pix >> 8, x = pix & 255;
    float acc[8];
    #pragma unroll
    for (int j = 0; j < 8; ++j) acc[j] = bsh[g * 8 + j];
    const float* zb = zf + (long)b * 131072;
    #pragma unroll
    for (int dy = 0; dy < 3; ++dy) {
        int yy = y + dy - 1;
        if ((unsigned)yy >= 256u) continue;
        #pragma unroll
        for (int dx = 0; dx < 3; ++dx) {
            int xx = x + dx - 1;
            if ((unsigned)xx >= 256u) continue;
            const float* p = zb + ((long)yy * 256 + xx) * 2;
            float v0 = p[0], v1 = p[1];
            int tap = dy * 3 + dx;
            #pragma unroll
            for (int j = 0; j < 8; ++j)
                acc[j] += v0 * wsh[0][tap][g*8+j] + v1 * wsh[1][tap][g*8+j];
        }
    }
    bf16x8 v;
    #pragma unroll
    for (int j = 0; j < 8; ++j) v[j] = (__bf16)fmaxf(acc[j], 0.f);
    *(bf16x8*)(outp + ((long)b * 65536 + pix) * 64 + g * 8) = v;
}

// ---------- final 1x1 conv (64->2) + residual + NHWC f32 store ------------
__global__ __launch_bounds__(256) void final_k(
    const bf16* __restrict__ X, const bf16* __restrict__ wfb,
    const float* __restrict__ zf, float* __restrict__ outp)
{
    __shared__ float wsh[128];
    __shared__ float bsh[2];
    const int t = threadIdx.x;
    const int i = blockIdx.x * 256 + t;
    const int pix = i & 65535;
    const int b = i >> 16;
    const long wb = (long)b * ODIM;
    if (t < 128) wsh[t] = b2f(wfb[wb + 590976 + t]);
    if (t < 2) bsh[t] = b2f(wfb[wb + 592000 + t]);
    __syncthreads();
    const bf16* p = X + ((long)b * 65536 + pix) * 64;
    float a0 = bsh[0], a1 = bsh[1];
    #pragma unroll
    for (int gq = 0; gq < 8; ++gq) {
        bf16x8 v = *(const bf16x8*)(p + gq * 8);
        #pragma unroll
        for (int j = 0; j < 8; ++j) {
            float f = (float)v[j];
            a0 += f * wsh[gq*8 + j];
            a1 += f * wsh[64 + gq*8 + j];
        }
    }
    long zi = ((long)b * 65536 + pix) * 2;
    outp[zi] = zf[zi] + a0;
    outp[zi + 1] = zf[zi + 1] + a1;
}

extern "C" void kernel_launch(void* const* d_in, const int* in_sizes, int n_in,
                              void* d_out, int out_size, void* d_ws, size_t ws_size,
                              hipStream_t stream)
{
    (void)in_sizes; (void)n_in; (void)out_size; (void)ws_size;
    const float* zf = (const float*)d_in[0];
    const float* hp = (const float*)d_in[2];
    const float* W1 = (const float*)d_in[3];
    const float* b1 = (const float*)d_in[4];
    const float* W2 = (const float*)d_in[5];
    const float* b2 = (const float*)d_in[6];
    const float* Wo = (const float*)d_in[7];
    const float* bo = (const float*)d_in[8];
    float* out = (float*)d_out;

    // ---- workspace carve (~218 MB) ----
    char* base = (char*)d_ws;
    float* h2   = (float*)base;  base += 1024;
    float* part = (float*)base;  base += 18504L * 4 + 32;
    bf16* wfb   = (bf16*)base;   base += 4736016L * 2 + 32;   // tanh weights (flat)
    bf16* WREP  = (bf16*)base;   base += 4718592L * 2;        // fragment-ordered weights
    bf16* Y256  = (bf16*)base;   base += 33554432L * 2;       // 8*256*256*64
    bf16* C1s   = (bf16*)base;   base += 33554432L * 2;
    bf16* D128a = (bf16*)base;   base += 8388608L * 2;        // 8*128*128*64
    bf16* C2s   = (bf16*)base;   base += 8388608L * 2;
    bf16* X128  = (bf16*)base;   base += 8388608L * 2;
    bf16* E64a  = (bf16*)base;   base += 2097152L * 2;        // 8*64*64*64
    bf16* C3s   = (bf16*)base;   base += 2097152L * 2;
    bf16* X64   = (bf16*)base;   base += 2097152L * 2;
    bf16* F32a  = (bf16*)base;   base += 524288L * 2;         // 8*32*32*64
    bf16* C4    = (bf16*)base;   base += 524288L * 2;

    hyper_h<<<1, 256, 0, stream>>>(hp, W1, b1, W2, b2, h2);
    const int ngb = (int)((ODIM + 255) / 256);   // 2313
    genw<<<ngb, 256, 0, stream>>>(Wo, bo, h2, wfb, part);
    l1_reduce<<<1, 256, 0, stream>>>(part, ngb, out + 1048576);

    const int BB = 591104;
    const long R1=0, R2=36864, R3=73728, R4=110592, R5=147456, R6=184320,
               R7=221184, R8=258048, R9=331776, R10=368640, R11=442368,
               R12=479232, R13=552960;

    repack_all<<<dim3(2304, 8), 256, 0, stream>>>(wfb, WREP);

    conv0_k<<<dim3(2048, 1, 8), 256, 0, stream>>>(zf, wfb, Y256);

    // encoder  (tile: TR=8, TC=32 -> 256 px/block, 43.5KB LDS, 3 blk/CU)
    conv_mfma<0><<<dim3(8,32,8),  256, 0, stream>>>(Y256, nullptr, 256,256, WREP, R1,  wfb, BB+64,  C1s);
    conv_mfma<1><<<dim3(4,16,8),  256, 0, stream>>>(C1s,  nullptr, 128,128, WREP, R2,  wfb, BB+128, D128a);
    conv_mfma<0><<<dim3(4,16,8),  256, 0, stream>>>(D128a,nullptr, 128,128, WREP, R3,  wfb, BB+192, C2s);
    conv_mfma<1><<<dim3(2,8,8),   256, 0, stream>>>(C2s,  nullptr, 64,64,   WREP, R4,  wfb, BB+256, E64a);
    conv_mfma<0><<<dim3(2,8,8),   256, 0, stream>>>(E64a, nullptr, 64,64,   WREP, R5,  wfb, BB+320, C3s);
    conv_mfma<1><<<dim3(1,4,8),   256, 0, stream>>>(C3s,  nullptr, 32,32,   WREP, R6,  wfb, BB+384, F32a);
    conv_mfma<0><<<dim3(1,4,8),   256, 0, stream>>>(F32a, nullptr, 32,32,   WREP, R7,  wfb, BB+448, C4);
    // decoder (UP fused into staging; concat = 2nd K-pass)
    conv_mfma<2><<<dim3(2,8,8),   256, 0, stream>>>(C4,   C3s, 64,64,   WREP, R8,  wfb, BB+512, E64a);
    conv_mfma<0><<<dim3(2,8,8),   256, 0, stream>>>(E64a, nullptr, 64,64, WREP, R9,  wfb, BB+576, X64);
    conv_mfma<2><<<dim3(4,16,8),  256, 0, stream>>>(X64,  C2s, 128,128, WREP, R10, wfb, BB+640, D128a);
    conv_mfma<0><<<dim3(4,16,8),  256, 0, stream>>>(D128a,nullptr,128,128, WREP, R11, wfb, BB+704, X128);
    conv_mfma<2><<<dim3(8,32,8),  256, 0, stream>>>(X128, C1s, 256,256, WREP, R12, wfb, BB+768, Y256);
    conv_mfma<0><<<dim3(8,32,8),  256, 0, stream>>>(Y256, nullptr,256,256, WREP, R13, wfb, BB+832, C1s);

    final_k<<<dim3(2048), 256, 0, stream>>>(C1s, wfb, zf, out);
}

// Round 13
// 523.266 us; speedup vs baseline: 1.4576x; 1.0627x over previous
//
#include <hip/hip_runtime.h>
#include <hip/hip_bf16.h>
#include <math.h>

#define ODIM 592002L
#define WRB  589824L
#define NB 8

typedef __hip_bfloat16 bf16;
typedef __bf16  bf16x8 __attribute__((ext_vector_type(8)));
typedef float   f32x16 __attribute__((ext_vector_type(16)));
typedef short   s16x8  __attribute__((ext_vector_type(8)));

__device__ __forceinline__ float b2f(bf16 x) { return __bfloat162float(x); }
__device__ __forceinline__ bf16 f2b(float x) { return __float2bfloat16(x); }
__device__ __forceinline__ bf16x8 bzero() { return __builtin_bit_cast(bf16x8, (s16x8)0); }

// ---------------- hypernet: h2 = (hp*W1^T + b1) @ W2^T + b2 ----------------
__global__ __launch_bounds__(256) void hyper_h(
    const float* __restrict__ hp, const float* __restrict__ W1,
    const float* __restrict__ b1, const float* __restrict__ W2,
    const float* __restrict__ b2, float* __restrict__ h2out)
{
    __shared__ float h1[NB][32];
    int t = threadIdx.x;
    int b = t >> 5, i = t & 31;
    h1[b][i] = hp[b] * W1[i] + b1[i];
    __syncthreads();
    float acc = b2[i];
    #pragma unroll
    for (int j = 0; j < 32; ++j) acc += h1[b][j] * W2[i * 32 + j];
    h2out[b * 32 + i] = acc;
}

// ------- w = tanh(h2 @ Wo^T + bo) -> bf16, + per-block |w| partials (f32) --
__global__ __launch_bounds__(256) void genw(
    const float* __restrict__ Wo, const float* __restrict__ bo,
    const float* __restrict__ h2, bf16* __restrict__ wfb,
    float* __restrict__ part)
{
    __shared__ float h2s[256];
    __shared__ float red[256];
    int t = threadIdx.x;
    h2s[t] = h2[t];
    __syncthreads();
    long o = (long)blockIdx.x * 256 + t;
    float absacc[NB];
    #pragma unroll
    for (int b = 0; b < NB; ++b) absacc[b] = 0.f;
    if (o < ODIM) {
        float row[32];
        const float4* wp = (const float4*)(Wo + o * 32);
        #pragma unroll
        for (int q = 0; q < 8; ++q) {
            float4 v = wp[q];
            row[q*4+0] = v.x; row[q*4+1] = v.y; row[q*4+2] = v.z; row[q*4+3] = v.w;
        }
        float bias = bo[o];
        #pragma unroll
        for (int b = 0; b < NB; ++b) {
            float acc = bias;
            #pragma unroll
            for (int k = 0; k < 32; ++k) acc += h2s[b*32+k] * row[k];
            float w = tanhf(acc);
            wfb[(long)b * ODIM + o] = f2b(w);
            absacc[b] = fabsf(w);
        }
    }
    for (int b = 0; b < NB; ++b) {
        red[t] = absacc[b];
        __syncthreads();
        for (int s = 128; s > 0; s >>= 1) {
            if (t < s) red[t] += red[t + s];
            __syncthreads();
        }
        if (t == 0) part[(long)blockIdx.x * NB + b] = red[0];
        __syncthreads();
    }
}

__global__ __launch_bounds__(256) void l1_reduce(
    const float* __restrict__ part, int nblk, float* __restrict__ outp)
{
    __shared__ float red[256];
    int t = threadIdx.x; int b = t & 7, ch = t >> 3;
    float s = 0.f;
    for (int i = ch; i < nblk; i += 32) s += part[(long)i * 8 + b];
    red[t] = s;
    __syncthreads();
    for (int st = 128; st >= 8; st >>= 1) {
        if (t < st) red[t] += red[t + st];
        __syncthreads();
    }
    if (t < 8) outp[t] = red[t];
}

// ---- repack ALL layers into per-lane MFMA fragment order (one launch) ----
// frag fid = ((pass*9 + tap)*4 + k4)*2 + oc_half ; then [lane][8].
__global__ __launch_bounds__(256) void repack_all(
    const bf16* __restrict__ wfb, bf16* __restrict__ wr)
{
    int i = blockIdx.x * 256 + threadIdx.x;   // 0..WRB-1
    int b = blockIdx.y;
    if (i >= (int)WRB) return;
    int roff, koff, dual = 0;
    if      (i < 36864)  { roff = 0;      koff = 1152;  }
    else if (i < 73728)  { roff = 36864;  koff = 38016; }
    else if (i < 110592) { roff = 73728;  koff = 74880; }
    else if (i < 147456) { roff = 110592; koff = 111744;}
    else if (i < 184320) { roff = 147456; koff = 148608;}
    else if (i < 221184) { roff = 184320; koff = 185472;}
    else if (i < 258048) { roff = 221184; koff = 222336;}
    else if (i < 331776) { roff = 258048; koff = 259200; dual = 1; }
    else if (i < 368640) { roff = 331776; koff = 332928;}
    else if (i < 442368) { roff = 368640; koff = 369792; dual = 1; }
    else if (i < 479232) { roff = 442368; koff = 443520;}
    else if (i < 552960) { roff = 479232; koff = 480384; dual = 1; }
    else                 { roff = 552960; koff = 554112;}
    int li = i - roff;
    int Cinfull = dual ? 128 : 64;
    int fid = li >> 9;
    int lane = (li >> 3) & 63;
    int j = li & 7;
    int h = fid & 1;
    int kk = fid >> 1;
    int k4 = kk & 3;
    int tapq = kk >> 2;
    int tap = tapq % 9;
    int pass = tapq / 9;
    int oc = h * 32 + (lane & 31);
    int icf = pass * 64 + k4 * 16 + (lane >> 5) * 8 + j;
    wr[(long)b * WRB + i] =
        wfb[(long)b * ODIM + koff + ((long)oc * Cinfull + icf) * 9 + tap];
}

// ---------------- LDS staging: PLAIN(0) / POOL(1) / UP2(2) ----------------
template<int TR, int TC, int MODE>
__device__ __forceinline__ void stage_tile(
    const bf16* __restrict__ src, int Hc, int Wc, int y0, int x0,
    bf16* lin, int t)
{
    const int XL = TC + 2;
    const int total = (TR + 2) * XL * 8;
    for (int idx = t; idx < total; idx += 256) {
        const int g = idx & 7;
        const int rem = idx >> 3;
        const int xl = rem % XL;
        const int gy = y0 + rem / XL - 1, gx = x0 + xl - 1;
        bf16x8 v = bzero();
        if ((unsigned)gy < (unsigned)Hc && (unsigned)gx < (unsigned)Wc) {
            if constexpr (MODE == 0) {
                v = *(const bf16x8*)(src + (((long)gy * Wc) + gx) * 64 + g * 8);
            } else if constexpr (MODE == 1) {
                const int Ws = Wc * 2;
                const bf16* p = src + (((long)(gy*2) * Ws) + gx*2) * 64 + g * 8;
                bf16x8 aa = *(const bf16x8*)p;
                bf16x8 bb = *(const bf16x8*)(p + 64);
                bf16x8 cc = *(const bf16x8*)(p + (long)Ws * 64);
                bf16x8 dd = *(const bf16x8*)(p + (long)Ws * 64 + 64);
                #pragma unroll
                for (int j = 0; j < 8; ++j) {
                    float m = fmaxf(fmaxf((float)aa[j], (float)bb[j]),
                                    fmaxf((float)cc[j], (float)dd[j]));
                    v[j] = (__bf16)m;
                }
            } else {
                const int Hs = Hc >> 1, Ws = Wc >> 1;
                const float sy = (float)(Hs - 1) / (float)(Hc - 1);
                const float sx = (float)(Ws - 1) / (float)(Wc - 1);
                float ys = gy * sy, xs = gx * sx;
                int yy0 = (int)ys, xx0 = (int)xs;
                int yy1 = min(yy0 + 1, Hs - 1), xx1 = min(xx0 + 1, Ws - 1);
                float wy = ys - (float)yy0, wx = xs - (float)xx0;
                bf16x8 q00 = *(const bf16x8*)(src + ((long)yy0*Ws + xx0)*64 + g*8);
                bf16x8 q01 = *(const bf16x8*)(src + ((long)yy0*Ws + xx1)*64 + g*8);
                bf16x8 q10 = *(const bf16x8*)(src + ((long)yy1*Ws + xx0)*64 + g*8);
                bf16x8 q11 = *(const bf16x8*)(src + ((long)yy1*Ws + xx1)*64 + g*8);
                #pragma unroll
                for (int j = 0; j < 8; ++j) {
                    float r0 = (float)q00[j]*(1.f-wx) + (float)q01[j]*wx;
                    float r1 = (float)q10[j]*(1.f-wx) + (float)q11[j]*wx;
                    v[j] = (__bf16)(r0*(1.f-wy) + r1*wy);
                }
            }
        }
        long byte = (((long)rem) * 128 + g * 16) ^ ((xl & 7) << 4);
        *(bf16x8*)((char*)lin + byte) = v;
    }
}

// ---------------- MFMA implicit-GEMM 3x3 conv, 64 oc, NHWC bf16 -----------
// Tile TR=4 x TC=32 = 128 px. 4 waves = (oc-half) x (2-row group). Per
// (k4,dxi,dy): ONE A-frag feeds TWO MFMAs. acc = 2 x f32x16 = 32 AGPR,
// arch ~65 -> fits (256,4) 128-reg budget -> 4 blk/CU = 16 waves/CU
// (occupancy was the invariant limiter: 3 structures all capped at 25%
// MfmaUtil @ 12 waves/CU). LDS 26KB. Paired waves load identical frags
// back-to-back -> L1 reuse halves L2 weight traffic.
template<int MODE>
__global__ __launch_bounds__(256, 4) void conv_mfma(
    const bf16* __restrict__ src1, const bf16* __restrict__ src2,
    int Hc, int Wc,
    const bf16* __restrict__ wr, long roff,
    const bf16* __restrict__ wfb, int boff,
    bf16* __restrict__ outp)
{
    const int TR = 4, TC = 32, XL = TC + 2;
    __shared__ bf16 lin[(TR + 2) * XL * 64];     // 26112 B
    __shared__ float biasf[64];
    const int t = threadIdx.x;
    const int lane = t & 63;
    const int w = t >> 6;
    const int half = w & 1;            // oc half
    const int wrow = (w >> 1) * 2;     // output rows wrow, wrow+1
    const int b = blockIdx.z;
    const int y0 = blockIdx.y * TR;
    const int x0 = blockIdx.x * TC;
    const int lx = lane & 31;

    f32x16 acc0 = {}, acc1 = {};

    const bf16* wl = wr + (long)b * WRB + roff;
    if (t < 64) biasf[t] = b2f(wfb[(long)b * ODIM + boff + t]);

    const int icbl = (lane >> 5) * 16;

    auto kpass = [&](int p) {
        #pragma unroll
        for (int k4 = 0; k4 < 4; ++k4) {
            #pragma unroll
            for (int dxi = 0; dxi < 3; ++dxi) {
                const int xl = lx + dxi;
                const int co = xl * 128 + ((k4 * 32 + icbl) ^ ((xl & 7) << 4));
                bf16x8 bfr[4];
                #pragma unroll
                for (int rr = 0; rr < 4; ++rr)
                    bfr[rr] = *(const bf16x8*)((const char*)lin + (wrow + rr) * (XL * 128) + co);
                #pragma unroll
                for (int dy = 0; dy < 3; ++dy) {
                    const int fid = ((p * 9 + dy * 3 + dxi) * 4 + k4) * 2 + half;
                    bf16x8 a0 = *(const bf16x8*)(wl + ((long)fid << 9) + (lane << 3));
                    acc0 = __builtin_amdgcn_mfma_f32_32x32x16_bf16(a0, bfr[dy + 0], acc0, 0, 0, 0);
                    acc1 = __builtin_amdgcn_mfma_f32_32x32x16_bf16(a0, bfr[dy + 1], acc1, 0, 0, 0);
                }
            }
        }
    };

    stage_tile<TR, TC, MODE>(src1, Hc, Wc, y0, x0, lin, t);
    __syncthreads();
    kpass(0);
    if (src2) {
        __syncthreads();
        stage_tile<TR, TC, 0>(src2, Hc, Wc, y0, x0, lin, t);
        __syncthreads();
        kpass(1);
    }

    // ---- epilogue: acc -> LDS [pix][oc] (swizzled) -> coalesced store ----
    __syncthreads();
    #pragma unroll
    for (int r = 0; r < 2; ++r) {
        const int pixidx = (wrow + r) * TC + lx;
        const int psw = (pixidx & 7) << 4;
        const f32x16& A = r ? acc1 : acc0;
        #pragma unroll
        for (int q = 0; q < 4; ++q) {
            const int oc0 = half * 32 + 8 * q + 4 * (lane >> 5);
            ushort4 pk;
            float v0 = fmaxf(A[4*q+0] + biasf[oc0 + 0], 0.f);
            float v1 = fmaxf(A[4*q+1] + biasf[oc0 + 1], 0.f);
            float v2 = fmaxf(A[4*q+2] + biasf[oc0 + 2], 0.f);
            float v3 = fmaxf(A[4*q+3] + biasf[oc0 + 3], 0.f);
            pk.x = __builtin_bit_cast(unsigned short, f2b(v0));
            pk.y = __builtin_bit_cast(unsigned short, f2b(v1));
            pk.z = __builtin_bit_cast(unsigned short, f2b(v2));
            pk.w = __builtin_bit_cast(unsigned short, f2b(v3));
            long byte = ((long)pixidx * 128 + oc0 * 2) ^ psw;
            *(ushort4*)((char*)lin + byte) = pk;
        }
    }
    __syncthreads();
    bf16* outt = outp + (((long)b * Hc + y0) * Wc + x0) * 64;
    #pragma unroll
    for (int off = t * 16; off < TR * TC * 128; off += 4096) {
        int pix = off >> 7;
        int r = pix >> 5, c = pix & 31;
        long sb = (long)off ^ ((pix & 7) << 4);
        bf16x8 v = *(const bf16x8*)((const char*)lin + sb);
        *(bf16x8*)((char*)outt + ((long)(r * Wc + c)) * 128 + (off & 127)) = v;
    }
}

// ---------------- conv0: 2->64 @256, zf f32 NHWC direct -------------------
__global__ __launch_bounds__(256) void conv0_k(
    const float* __restrict__ zf, const bf16* __restrict__ wfb,
    bf16* __restrict__ outp)
{
    __shared__ float wsh[2][9][64];
    __shared__ float bsh[64];
    const int t = threadIdx.x;
    const int b = blockIdx.z;
    const long wb = (long)b * ODIM;
    for (int i = t; i < 1152; i += 256) {
        int oc = i / 18, r2 = i % 18, ic = r2 / 9, tap = r2 % 9;
        wsh[ic][tap][oc] = b2f(wfb[wb + i]);
    }
    if (t < 64) bsh[t] = b2f(wfb[wb + 591104 + t]);
    __syncthreads();
    const int pl = t >> 3, g = t & 7;
    const int pix = blockIdx.x * 32 + pl;
    const int y = pix >> 8, x = pix & 255;
    float acc[8];
    #pragma unroll
    for (int j = 0; j < 8; ++j) acc[j] = bsh[g * 8 + j];
    const float* zb = zf + (long)b * 131072;
    #pragma unroll
    for (int dy = 0; dy < 3; ++dy) {
        int yy = y + dy - 1;
        if ((unsigned)yy >= 256u) continue;
        #pragma unroll
        for (int dx = 0; dx < 3; ++dx) {
            int xx = x + dx - 1;
            if ((unsigned)xx >= 256u) continue;
            const float* p = zb + ((long)yy * 256 + xx) * 2;
            float v0 = p[0], v1 = p[1];
            int tap = dy * 3 + dx;
            #pragma unroll
            for (int j = 0; j < 8; ++j)
                acc[j] += v0 * wsh[0][tap][g*8+j] + v1 * wsh[1][tap][g*8+j];
        }
    }
    bf16x8 v;
    #pragma unroll
    for (int j = 0; j < 8; ++j) v[j] = (__bf16)fmaxf(acc[j], 0.f);
    *(bf16x8*)(outp + ((long)b * 65536 + pix) * 64 + g * 8) = v;
}

// ---------- final 1x1 conv (64->2) + residual + NHWC f32 store ------------
__global__ __launch_bounds__(256) void final_k(
    const bf16* __restrict__ X, const bf16* __restrict__ wfb,
    const float* __restrict__ zf, float* __restrict__ outp)
{
    __shared__ float wsh[128];
    __shared__ float bsh[2];
    const int t = threadIdx.x;
    const int i = blockIdx.x * 256 + t;
    const int pix = i & 65535;
    const int b = i >> 16;
    const long wb = (long)b * ODIM;
    if (t < 128) wsh[t] = b2f(wfb[wb + 590976 + t]);
    if (t < 2) bsh[t] = b2f(wfb[wb + 592000 + t]);
    __syncthreads();
    const bf16* p = X + ((long)b * 65536 + pix) * 64;
    float a0 = bsh[0], a1 = bsh[1];
    #pragma unroll
    for (int gq = 0; gq < 8; ++gq) {
        bf16x8 v = *(const bf16x8*)(p + gq * 8);
        #pragma unroll
        for (int j = 0; j < 8; ++j) {
            float f = (float)v[j];
            a0 += f * wsh[gq*8 + j];
            a1 += f * wsh[64 + gq*8 + j];
        }
    }
    long zi = ((long)b * 65536 + pix) * 2;
    outp[zi] = zf[zi] + a0;
    outp[zi + 1] = zf[zi + 1] + a1;
}

extern "C" void kernel_launch(void* const* d_in, const int* in_sizes, int n_in,
                              void* d_out, int out_size, void* d_ws, size_t ws_size,
                              hipStream_t stream)
{
    (void)in_sizes; (void)n_in; (void)out_size; (void)ws_size;
    const float* zf = (const float*)d_in[0];
    const float* hp = (const float*)d_in[2];
    const float* W1 = (const float*)d_in[3];
    const float* b1 = (const float*)d_in[4];
    const float* W2 = (const float*)d_in[5];
    const float* b2 = (const float*)d_in[6];
    const float* Wo = (const float*)d_in[7];
    const float* bo = (const float*)d_in[8];
    float* out = (float*)d_out;

    // ---- workspace carve (~218 MB) ----
    char* base = (char*)d_ws;
    float* h2   = (float*)base;  base += 1024;
    float* part = (float*)base;  base += 18504L * 4 + 32;
    bf16* wfb   = (bf16*)base;   base += 4736016L * 2 + 32;   // tanh weights (flat)
    bf16* WREP  = (bf16*)base;   base += 4718592L * 2;        // fragment-ordered weights
    bf16* Y256  = (bf16*)base;   base += 33554432L * 2;       // 8*256*256*64
    bf16* C1s   = (bf16*)base;   base += 33554432L * 2;
    bf16* D128a = (bf16*)base;   base += 8388608L * 2;        // 8*128*128*64
    bf16* C2s   = (bf16*)base;   base += 8388608L * 2;
    bf16* X128  = (bf16*)base;   base += 8388608L * 2;
    bf16* E64a  = (bf16*)base;   base += 2097152L * 2;        // 8*64*64*64
    bf16* C3s   = (bf16*)base;   base += 2097152L * 2;
    bf16* X64   = (bf16*)base;   base += 2097152L * 2;
    bf16* F32a  = (bf16*)base;   base += 524288L * 2;         // 8*32*32*64
    bf16* C4    = (bf16*)base;   base += 524288L * 2;

    hyper_h<<<1, 256, 0, stream>>>(hp, W1, b1, W2, b2, h2);
    const int ngb = (int)((ODIM + 255) / 256);   // 2313
    genw<<<ngb, 256, 0, stream>>>(Wo, bo, h2, wfb, part);
    l1_reduce<<<1, 256, 0, stream>>>(part, ngb, out + 1048576);

    const int BB = 591104;
    const long R1=0, R2=36864, R3=73728, R4=110592, R5=147456, R6=184320,
               R7=221184, R8=258048, R9=331776, R10=368640, R11=442368,
               R12=479232, R13=552960;

    repack_all<<<dim3(2304, 8), 256, 0, stream>>>(wfb, WREP);

    conv0_k<<<dim3(2048, 1, 8), 256, 0, stream>>>(zf, wfb, Y256);

    // encoder  (tile: TR=4, TC=32 -> 128 px/block, 26KB LDS, 4 blk/CU)
    conv_mfma<0><<<dim3(8,64,8),  256, 0, stream>>>(Y256, nullptr, 256,256, WREP, R1,  wfb, BB+64,  C1s);
    conv_mfma<1><<<dim3(4,32,8),  256, 0, stream>>>(C1s,  nullptr, 128,128, WREP, R2,  wfb, BB+128, D128a);
    conv_mfma<0><<<dim3(4,32,8),  256, 0, stream>>>(D128a,nullptr, 128,128, WREP, R3,  wfb, BB+192, C2s);
    conv_mfma<1><<<dim3(2,16,8),  256, 0, stream>>>(C2s,  nullptr, 64,64,   WREP, R4,  wfb, BB+256, E64a);
    conv_mfma<0><<<dim3(2,16,8),  256, 0, stream>>>(E64a, nullptr, 64,64,   WREP, R5,  wfb, BB+320, C3s);
    conv_mfma<1><<<dim3(1,8,8),   256, 0, stream>>>(C3s,  nullptr, 32,32,   WREP, R6,  wfb, BB+384, F32a);
    conv_mfma<0><<<dim3(1,8,8),   256, 0, stream>>>(F32a, nullptr, 32,32,   WREP, R7,  wfb, BB+448, C4);
    // decoder (UP fused into staging; concat = 2nd K-pass)
    conv_mfma<2><<<dim3(2,16,8),  256, 0, stream>>>(C4,   C3s, 64,64,   WREP, R8,  wfb, BB+512, E64a);
    conv_mfma<0><<<dim3(2,16,8),  256, 0, stream>>>(E64a, nullptr, 64,64, WREP, R9,  wfb, BB+576, X64);
    conv_mfma<2><<<dim3(4,32,8),  256, 0, stream>>>(X64,  C2s, 128,128, WREP, R10, wfb, BB+640, D128a);
    conv_mfma<0><<<dim3(4,32,8),  256, 0, stream>>>(D128a,nullptr,128,128, WREP, R11, wfb, BB+704, X128);
    conv_mfma<2><<<dim3(8,64,8),  256, 0, stream>>>(X128, C1s, 256,256, WREP, R12, wfb, BB+768, Y256);
    conv_mfma<0><<<dim3(8,64,8),  256, 0, stream>>>(Y256, nullptr,256,256, WREP, R13, wfb, BB+832, C1s);

    final_k<<<dim3(2048), 256, 0, stream>>>(C1s, wfb, zf, out);
}